// Round 7
// baseline (106.620 us; speedup 1.0000x reference)
//
#include <hip/hip_runtime.h>

typedef _Float16 h8 __attribute__((ext_vector_type(8)));
typedef _Float16 h4 __attribute__((ext_vector_type(4)));
typedef float f4 __attribute__((ext_vector_type(4)));
typedef unsigned int uint32;

#define NT 7        // n-tiles: 112 output features (100 real)
#define KC 4        // k-chunks of 32: k=0..99 real, k=100 -> t, k=101 -> 1
#define HSTRIDE 104 // 52 words/row; 208 B rows -> every row 16B-aligned

__global__ __launch_bounds__(256, 2)
void grnn_fused(const float* __restrict__ times,
                const float* __restrict__ Qw,
                const float* __restrict__ Qb,
                const float* __restrict__ Ww,
                const float* __restrict__ Wb,
                const float* __restrict__ Pw,
                const float* __restrict__ Pb,
                float* __restrict__ out)
{
  // Comb double-buffer: level d reads base R, writes base W=128-R (one
  // barrier per level; WAR safe because reads precede writes in program
  // order and the barrier separates levels). Row = comb row (sibling sum).
  __shared__ __align__(16) _Float16 Cs[192][HSTRIDE]; // 39936 B
  __shared__ __align__(8)  _Float16 ts[1026];         // f16 times at +1 offset
  __shared__ __align__(16) float qw_s[128];           // zero-padded
  __shared__ __align__(16) float qb_s[128];

  const int tid  = threadIdx.x;
  const int wave = tid >> 6;
  const int lane = tid & 63;
  const int l15  = lane & 15;
  const int kg   = lane >> 4;
  const int tree = blockIdx.x;

  // ---- phase 0: stage times (f16) and Q vectors ----
  {
    const float* tg = times + tree * 1023;
    for (int i = tid; i < 1023; i += 256) ts[1 + i] = (_Float16)tg[i];
    if (tid == 0) ts[0] = (_Float16)0.f;
    if (tid < 128) {
      float qw = 0.f, qb = 0.f;
      if (tid < 100) { qw = Qw[tid]; qb = Qb[tid]; }
      qw_s[tid] = qw; qb_s[tid] = qb;
    }
  }

  // ---- persistent W fragments from global (B[k][n] = Ww[n][k]);
  //      fold rows: B[100][n] = Qw[n], B[101][n] = Qb[n] + Wb[n] ----
  h8 wf[NT][KC];
  #pragma unroll
  for (int nt = 0; nt < NT; ++nt) {
    const int r = nt * 16 + l15;           // output feature (Ww row)
    #pragma unroll
    for (int kc = 0; kc < KC; ++kc) {
      h8 v;
      #pragma unroll
      for (int j = 0; j < 8; ++j) v[j] = (_Float16)0.f;
      if (r < 100) {
        const int kb = kc * 32 + kg * 8;
        if (kc < 3) {
          const f4 w0 = *(const f4*)&Ww[r * 100 + kb];
          const f4 w1 = *(const f4*)&Ww[r * 100 + kb + 4];
          #pragma unroll
          for (int j = 0; j < 4; ++j) {
            v[j]     = (_Float16)w0[j];
            v[j + 4] = (_Float16)w1[j];
          }
        } else if (kg == 0) {              // k = 96..103
          const f4 w0 = *(const f4*)&Ww[r * 100 + 96];
          #pragma unroll
          for (int j = 0; j < 4; ++j) v[j] = (_Float16)w0[j];
          v[4] = (_Float16)Qw[r];          // k=100
          v[5] = (_Float16)(Qb[r] + Wb[r]);// k=101
        }
      }
      wf[nt][kc] = v;
    }
  }
  __syncthreads();

// Swapped-operand MFMA: lane(l15,kg) reg r holds feature nt*16+kg*4+r of
// node MT*16+l15. Epilogue: ReLU, sibling pair-add (lane^1 = node^1), even
// l15 lanes store the comb row. nt==6: only kg==0 holds real features.
#define DO_MT(MT, LO, HI, WB) do {                                            \
    _Pragma("unroll")                                                         \
    for (int nt_ = 0; nt_ < NT; ++nt_) {                                      \
      if (nt_ >= (LO) && nt_ < (HI)) {                                        \
        f4 acc_ = {0.f, 0.f, 0.f, 0.f};                                       \
        _Pragma("unroll")                                                     \
        for (int kc_ = 0; kc_ < KC; ++kc_)                                    \
          acc_ = __builtin_amdgcn_mfma_f32_16x16x32_f16(wf[nt_][kc_],         \
                                                        af[kc_], acc_, 0,0,0);\
        if (nt_ < 6 || kg == 0) {                                             \
          h4 hv_ = {(_Float16)fmaxf(acc_[0], 0.f),                            \
                    (_Float16)fmaxf(acc_[1], 0.f),                            \
                    (_Float16)fmaxf(acc_[2], 0.f),                            \
                    (_Float16)fmaxf(acc_[3], 0.f)};                           \
          uint2 u_ = __builtin_bit_cast(uint2, hv_);                          \
          u_.x = __shfl_xor(u_.x, 1, 64);                                     \
          u_.y = __shfl_xor(u_.y, 1, 64);                                     \
          hv_ = hv_ + __builtin_bit_cast(h4, u_);                             \
          if ((l15 & 1) == 0)                                                 \
            *(h4*)&Cs[(WB) + (MT) * 8 + (l15 >> 1)][nt_ * 16 + kg * 4] = hv_; \
        }                                                                     \
      }                                                                       \
    }                                                                         \
  } while (0)

// Root: store h itself (no pair-add), node 0 = l15 0, into row 0.
#define DO_MT_ROOT(LO, HI) do {                                               \
    _Pragma("unroll")                                                         \
    for (int nt_ = 0; nt_ < NT; ++nt_) {                                      \
      if (nt_ >= (LO) && nt_ < (HI)) {                                        \
        f4 acc_ = {0.f, 0.f, 0.f, 0.f};                                       \
        _Pragma("unroll")                                                     \
        for (int kc_ = 0; kc_ < KC; ++kc_)                                    \
          acc_ = __builtin_amdgcn_mfma_f32_16x16x32_f16(wf[nt_][kc_],         \
                                                        af[kc_], acc_, 0,0,0);\
        if ((nt_ < 6 || kg == 0) && l15 == 0) {                               \
          h4 hv_ = {(_Float16)fmaxf(acc_[0], 0.f),                            \
                    (_Float16)fmaxf(acc_[1], 0.f),                            \
                    (_Float16)fmaxf(acc_[2], 0.f),                            \
                    (_Float16)fmaxf(acc_[3], 0.f)};                           \
          *(h4*)&Cs[0][nt_ * 16 + kg * 4] = hv_;                              \
        }                                                                     \
      }                                                                       \
    }                                                                         \
  } while (0)

// af[m=node l15][k]: k<100 -> comb row (RB+m); k=100 -> t(node m); k=101 -> 1
#define LOAD_AFR(MT, S, RB) do {                                              \
    const int row_ = (RB) + (MT) * 16 + l15;                                  \
    _Pragma("unroll")                                                         \
    for (int kc_ = 0; kc_ < 3; ++kc_)                                         \
      af[kc_] = *(const h8*)&Cs[row_][kc_ * 32 + kg * 8];                     \
    if (kg == 0) {                                                            \
      h4 lo_ = *(const h4*)&Cs[row_][96];                                     \
      h4 hi_ = {ts[1 + (S) + (MT) * 16 + l15], (_Float16)1.f,                 \
                (_Float16)0.f, (_Float16)0.f};                                \
      af[3] = __builtin_shufflevector(lo_, hi_, 0, 1, 2, 3, 4, 5, 6, 7);      \
    } else {                                                                  \
      _Pragma("unroll")                                                       \
      for (int j_ = 0; j_ < 8; ++j_) af[3][j_] = (_Float16)0.f;               \
    }                                                                         \
  } while (0)

  // ---- level 8 (256 nodes): leaves fused in VALU; 16 m-tiles, 4/wave;
  //      writes comb rows 0..127 (W base 0) ----
  #pragma unroll 1
  for (int i = 0; i < 4; ++i) {
    const int mt = wave + 4 * i;
    const int m  = mt * 16 + l15;
    const uint32 tp = *(const uint32*)&ts[512 + 2 * m]; // leaf pair (aligned)
    const float t0 = (float)*(const _Float16*)&tp;
    const float t1 = (float)*((const _Float16*)&tp + 1);
    h8 af[KC];
    #pragma unroll
    for (int kc = 0; kc < KC; ++kc) {
      const int kb = kc * 32 + kg * 8;
      const f4 qwa = *(const f4*)&qw_s[kb];
      const f4 qwb = *(const f4*)&qw_s[kb + 4];
      const f4 qba = *(const f4*)&qb_s[kb];
      const f4 qbb = *(const f4*)&qb_s[kb + 4];
      #pragma unroll
      for (int j = 0; j < 4; ++j) {
        float h0 = fmaxf(t0 * qwa[j] + qba[j], 0.f);
        float h1 = fmaxf(t1 * qwa[j] + qba[j], 0.f);
        af[kc][j] = (_Float16)(h0 + h1);
        float g0 = fmaxf(t0 * qwb[j] + qbb[j], 0.f);
        float g1 = fmaxf(t1 * qwb[j] + qbb[j], 0.f);
        af[kc][j + 4] = (_Float16)(g0 + g1);
      }
    }
    if (kg == 0) {                       // fold slots k=100,101
      af[3][4] = ts[1 + 255 + m];
      af[3][5] = (_Float16)1.f;
      af[3][6] = (_Float16)0.f;
      af[3][7] = (_Float16)0.f;
    }
    DO_MT(mt, 0, NT, 0);
  }
  __syncthreads();

  // ---- levels 7..1: one barrier per level; all waves busy every level ----
  #pragma unroll 1
  for (int d = 7; d >= 1; --d) {
    const int s  = (1 << d) - 1;
    const int R  = ((7 - d) & 1) ? 128 : 0;
    const int W  = 128 - R;
    const int nm = (d >= 4) ? (1 << (d - 4)) : 1;
    h8 af[KC];
    if (nm >= 4) {                        // 1-2 full tiles per wave
      LOAD_AFR(wave, s, R);
      DO_MT(wave, 0, NT, W);
      if (nm == 8) {
        LOAD_AFR(wave + 4, s, R);
        DO_MT(wave + 4, 0, NT, W);
      }
    } else if (nm == 2) {                 // 2 tiles x nt-halves over 4 waves
      const int mt = wave & 1;
      const int lo = (wave < 2) ? 0 : 4;
      const int hi = (wave < 2) ? 4 : NT;
      LOAD_AFR(mt, s, R);
      DO_MT(mt, lo, hi, W);
    } else {                              // 1 tile x nt-quarters over 4 waves
      const int lo = 2 * wave;
      const int hi = (wave == 3) ? NT : 2 * wave + 2;
      LOAD_AFR(0, s, R);
      DO_MT(0, lo, hi, W);
    }
    __syncthreads();
  }

  // ---- root (d=0): read comb row 128, store h into row 0 ----
  {
    h8 af[KC];
    const int lo = 2 * wave;
    const int hi = (wave == 3) ? NT : 2 * wave + 2;
    LOAD_AFR(0, 0, 128);
    DO_MT_ROOT(lo, hi);
  }
  __syncthreads();

  // ---- projection: out[p] = root . Pw[p] + Pb[p], p<5 ----
  if (tid < 160) {
    const int p = tid >> 5;
    const int j = tid & 31;
    float sum = 0.f;
    #pragma unroll
    for (int c = 0; c < 4; ++c) {
      const int o = j + 32 * c;
      if (o < 100) sum += (float)Cs[0][o] * Pw[p * 100 + o];
    }
    sum += __shfl_down(sum, 16, 32);
    sum += __shfl_down(sum, 8, 32);
    sum += __shfl_down(sum, 4, 32);
    sum += __shfl_down(sum, 2, 32);
    sum += __shfl_down(sum, 1, 32);
    if (j == 0) out[tree * 5 + p] = sum + Pb[p];
  }
#undef DO_MT
#undef DO_MT_ROOT
#undef LOAD_AFR
}

extern "C" void kernel_launch(void* const* d_in, const int* in_sizes, int n_in,
                              void* d_out, int out_size, void* d_ws, size_t ws_size,
                              hipStream_t stream) {
  (void)n_in; (void)out_size; (void)d_ws; (void)ws_size;
  const float* times = (const float*)d_in[0];
  const float* Qw = (const float*)d_in[1];
  const float* Qb = (const float*)d_in[2];
  const float* Ww = (const float*)d_in[3];
  const float* Wb = (const float*)d_in[4];
  const float* Pw = (const float*)d_in[5];
  const float* Pb = (const float*)d_in[6];
  float* outp = (float*)d_out;
  const int B = in_sizes[0] / 1023;   // 1024 trees
  grnn_fused<<<dim3(B), dim3(256), 0, stream>>>(times, Qw, Qb, Ww, Wb, Pw, Pb, outp);
}